// Round 1
// baseline (99.302 us; speedup 1.0000x reference)
//
#include <hip/hip_runtime.h>

typedef __bf16 bf16x4 __attribute__((ext_vector_type(4)));
typedef __bf16 bf16x8 __attribute__((ext_vector_type(8)));
typedef float  f32x4  __attribute__((ext_vector_type(4)));

#define WCS 68   // LDS row stride (bf16 elems) for Wc^T: 64 + 4 pad -> conflict-free b64
#define XS  68   // LDS row stride for X tile

// Grid = 512 (one block per batch row b), 256 threads (4 waves).
// Wave w owns hidden-group hg = w (h = w*16 .. w*16+15); iterates e = 0..7
// over column tiles c = e*64 + w*16 + n. Each wave computes all 64 rows of the
// s-tile (4 row-tiles x 16x16 MFMA tiles), LeakyReLU + max-over-e in regs,
// then shuffle-reduces the row sum. After 4 s-tiles the block holds the full
// t0[b][0..63]; wave 0 applies fc1 in-block.
__global__ __launch_bounds__(256, 2)
void fused_main(const float* __restrict__ X, const float* __restrict__ Wc,
                const float* __restrict__ fc1_w, const float* __restrict__ fc1_b,
                float* __restrict__ out1)
{
    __shared__ __bf16 wclds[512 * WCS];   // 69632 B : wclds[c*WCS + k] = Wc[k][c]
    __shared__ __bf16 xlds[64 * XS];      //  8704 B : xlds[r*XS + k]  = X[b][s0+r][k]
    __shared__ float  t0row[64];

    const int tid  = threadIdx.x;
    const int b    = blockIdx.x;
    const int wave = tid >> 6;
    const int lane = tid & 63;
    const int n    = lane & 15;
    const int q    = lane >> 4;

    // ---- stage Wc^T as bf16 (transpose: each thread handles 2 full columns) ----
    // Global reads: per (kc,j) instruction, lanes read consecutive c -> coalesced, L2-hot.
    #pragma unroll
    for (int cc = 0; cc < 2; ++cc) {
        const int c = tid + cc * 256;
        #pragma unroll
        for (int kc = 0; kc < 8; ++kc) {
            bf16x4 lo, hi;
            #pragma unroll
            for (int j = 0; j < 4; ++j) lo[j] = (__bf16)Wc[(kc * 8 + j) * 512 + c];
            #pragma unroll
            for (int j = 0; j < 4; ++j) hi[j] = (__bf16)Wc[(kc * 8 + 4 + j) * 512 + c];
            *(bf16x4*)&wclds[c * WCS + kc * 8]     = lo;
            *(bf16x4*)&wclds[c * WCS + kc * 8 + 4] = hi;
        }
    }

    float hsum = 0.0f;   // running sum over S for col h = wave*16 + n (valid in all quads)

    for (int st = 0; st < 4; ++st) {
        // ---- stage X tile (64 rows x 64 k), fp32 -> bf16, fully coalesced ----
        const float4* xg = (const float4*)(X + ((size_t)b * 256 + (size_t)st * 64) * 64);
        #pragma unroll
        for (int i = 0; i < 4; ++i) {
            const int p = tid + i * 256;          // float4 index within 16KB tile
            float4 v = xg[p];
            bf16x4 o;
            o[0] = (__bf16)v.x; o[1] = (__bf16)v.y;
            o[2] = (__bf16)v.z; o[3] = (__bf16)v.w;
            const int r = p >> 4, ck = p & 15;
            *(bf16x4*)&xlds[r * XS + ck * 4] = o;
        }
        __syncthreads();   // also covers Wc staging on st==0

        // ---- A fragments: 4 row-tiles, k-halves 0..31 / 32..63 (reused over 8 e's) ----
        bf16x8 a0[4], a1[4];
        #pragma unroll
        for (int t = 0; t < 4; ++t) {
            const int base = (t * 16 + n) * XS + q * 8;
            bf16x4 p0 = *(const bf16x4*)&xlds[base];
            bf16x4 p1 = *(const bf16x4*)&xlds[base + 4];
            bf16x4 p2 = *(const bf16x4*)&xlds[base + 32];
            bf16x4 p3 = *(const bf16x4*)&xlds[base + 36];
            a0[t] = __builtin_shufflevector(p0, p1, 0, 1, 2, 3, 4, 5, 6, 7);
            a1[t] = __builtin_shufflevector(p2, p3, 0, 1, 2, 3, 4, 5, 6, 7);
        }

        float rmax[4][4];
        #pragma unroll
        for (int t = 0; t < 4; ++t)
            #pragma unroll
            for (int r4 = 0; r4 < 4; ++r4) rmax[t][r4] = -3.0e38f;

        for (int e = 0; e < 8; ++e) {
            const int c    = e * 64 + wave * 16 + n;
            const int base = c * WCS + q * 8;
            bf16x4 p0 = *(const bf16x4*)&wclds[base];
            bf16x4 p1 = *(const bf16x4*)&wclds[base + 4];
            bf16x4 p2 = *(const bf16x4*)&wclds[base + 32];
            bf16x4 p3 = *(const bf16x4*)&wclds[base + 36];
            bf16x8 b0 = __builtin_shufflevector(p0, p1, 0, 1, 2, 3, 4, 5, 6, 7);
            bf16x8 b1 = __builtin_shufflevector(p2, p3, 0, 1, 2, 3, 4, 5, 6, 7);
            #pragma unroll
            for (int t = 0; t < 4; ++t) {
                f32x4 acc = {0.f, 0.f, 0.f, 0.f};
                acc = __builtin_amdgcn_mfma_f32_16x16x32_bf16(a0[t], b0, acc, 0, 0, 0);
                acc = __builtin_amdgcn_mfma_f32_16x16x32_bf16(a1[t], b1, acc, 0, 0, 0);
                #pragma unroll
                for (int r4 = 0; r4 < 4; ++r4) {
                    float v = acc[r4];
                    v = fmaxf(v, 0.01f * v);               // LeakyReLU(x) = max(x, 0.01x)
                    rmax[t][r4] = fmaxf(rmax[t][r4], v);   // max over e
                }
            }
        }

        // sum this s-tile's 64 rows: 16 rows per lane, then butterfly across quads
        float s = 0.f;
        #pragma unroll
        for (int t = 0; t < 4; ++t)
            #pragma unroll
            for (int r4 = 0; r4 < 4; ++r4) s += rmax[t][r4];
        s += __shfl_xor(s, 16);
        s += __shfl_xor(s, 32);
        hsum += s;
        __syncthreads();   // xlds reused next s-tile
    }

    if (lane < 16) t0row[wave * 16 + lane] = hsum;
    __syncthreads();

    // ---- fc1 in-block: out1[b][j] = fc1_b[j] + sum_h t0[h] * fc1_w[j][h] ----
    if (wave == 0) {
        const int j = lane & 31, half = lane >> 5;
        float p = 0.f;
        #pragma unroll
        for (int i = 0; i < 32; ++i)
            p += t0row[half * 32 + i] * fc1_w[j * 64 + half * 32 + i];
        p += __shfl_xor(p, 32);
        if (half == 0) out1[b * 32 + j] = p + fc1_b[j];
    }
}

// Single block: BatchNorm (training-mode batch stats, biased var) + LeakyReLU + fc2
__global__ __launch_bounds__(512)
void bn_fc2(const float* __restrict__ out1, const float* __restrict__ gamma,
            const float* __restrict__ beta, const float* __restrict__ fc2_w,
            const float* __restrict__ fc2_b, float* __restrict__ out)
{
    __shared__ float psum[16][32];
    __shared__ float psumsq[16][32];
    __shared__ float sa[32], sc[32];

    const int tid = threadIdx.x;
    const int j   = tid & 31;
    const int sl  = tid >> 5;       // 16 slices of 32 batch rows

    float s = 0.f, ss = 0.f;
    #pragma unroll
    for (int i = 0; i < 32; ++i) {
        float v = out1[(sl * 32 + i) * 32 + j];
        s  += v;
        ss += v * v;
    }
    psum[sl][j]   = s;
    psumsq[sl][j] = ss;
    __syncthreads();

    if (tid < 32) {
        float S = 0.f, SS = 0.f;
        #pragma unroll
        for (int i = 0; i < 16; ++i) { S += psum[i][tid]; SS += psumsq[i][tid]; }
        const float mu  = S * (1.0f / 512.0f);
        const float var = SS * (1.0f / 512.0f) - mu * mu;   // biased variance
        const float rs  = rsqrtf(var + 1e-5f);
        const float a   = rs * gamma[tid];
        sa[tid] = a;
        sc[tid] = beta[tid] - mu * a;
    }
    __syncthreads();

    // one thread per batch row
    float acc = 0.f;
    #pragma unroll
    for (int jj = 0; jj < 32; ++jj) {
        float v = out1[tid * 32 + jj];
        float y = v * sa[jj] + sc[jj];
        y = fmaxf(y, 0.01f * y);    // LeakyReLU
        acc += y * fc2_w[jj];
    }
    out[tid] = acc + fc2_b[0];
}

extern "C" void kernel_launch(void* const* d_in, const int* in_sizes, int n_in,
                              void* d_out, int out_size, void* d_ws, size_t ws_size,
                              hipStream_t stream) {
    const float* X      = (const float*)d_in[0];
    const float* Wc     = (const float*)d_in[1];
    const float* fc1_w  = (const float*)d_in[2];
    const float* fc1_b  = (const float*)d_in[3];
    const float* gamma  = (const float*)d_in[4];
    const float* beta   = (const float*)d_in[5];
    const float* fc2_w  = (const float*)d_in[6];
    const float* fc2_b  = (const float*)d_in[7];

    float* out1 = (float*)d_ws;   // [512][32] fc1 outputs, 64 KB

    fused_main<<<512, 256, 0, stream>>>(X, Wc, fc1_w, fc1_b, out1);
    bn_fc2<<<1, 512, 0, stream>>>(out1, gamma, beta, fc2_w, fc2_b, (float*)d_out);
}

// Round 2
// 99.266 us; speedup vs baseline: 1.0004x; 1.0004x over previous
//
#include <hip/hip_runtime.h>

typedef __bf16 bf16x4 __attribute__((ext_vector_type(4)));
typedef __bf16 bf16x8 __attribute__((ext_vector_type(8)));
typedef float  f32x4  __attribute__((ext_vector_type(4)));

#define XS 68   // LDS row stride (bf16 elems) for X tile: 64 + 4 pad

// Grid = 512 (one block per batch row b), 256 threads (4 waves).
// B fragments (Wc columns for this wave's 8 e-tiles) live entirely in
// registers (64 VGPRs/lane) -> no Wc LDS staging, LDS = 8.9 KB.
// Wave w owns h = w*16 + n; per s-tile computes 4 16x16 row-tiles via
// mfma_f32_16x16x32_bf16, LeakyReLU + max-over-e fused as v_max3,
// shuffle-reduces the S-sum; wave 0 applies fc1 in-block at the end.
__global__ __launch_bounds__(256, 2)
void fused_main(const float* __restrict__ X, const float* __restrict__ Wc,
                const float* __restrict__ fc1_w, const float* __restrict__ fc1_b,
                float* __restrict__ out1)
{
    __shared__ __bf16 xlds[64 * XS];      // 8704 B : xlds[r*XS + k] = X[b][s0+r][k]
    __shared__ float  t0row[64];

    const int tid  = threadIdx.x;
    const int b    = blockIdx.x;
    const int wave = tid >> 6;
    const int lane = tid & 63;
    const int n    = lane & 15;
    const int q    = lane >> 4;

    const float4* xg = (const float4*)(X + (size_t)b * 256 * 64);

    // ---- prefetch X tile 0 into registers (HBM, longest latency first) ----
    float4 xv[4];
    #pragma unroll
    for (int i = 0; i < 4; ++i) xv[i] = xg[tid + i * 256];

    // ---- B fragments straight to registers: bf0/bf1[e][j] = Wc[k][c] ----
    // lane (n,q) holds cols c = e*64 + wave*16 + n, k = q*8+j (+32 for bf1).
    // For fixed (e,j) a quad's 16 lanes read 64 consecutive bytes; Wc is
    // 131 KB -> L2-hot after first touch.
    bf16x8 bf0[8], bf1[8];
    {
        const float* wbase = Wc + (q * 8) * 512 + wave * 16 + n;
        #pragma unroll
        for (int e = 0; e < 8; ++e) {
            const float* p = wbase + e * 64;
            #pragma unroll
            for (int j = 0; j < 8; ++j) {
                bf0[e][j] = (__bf16)p[j * 512];
                bf1[e][j] = (__bf16)p[(j + 32) * 512];
            }
        }
    }

    float hsum = 0.0f;   // running sum over S for col h = wave*16 + n

    for (int st = 0; st < 4; ++st) {
        // ---- commit prefetched tile to LDS (fp32 -> bf16) ----
        #pragma unroll
        for (int i = 0; i < 4; ++i) {
            const int p = tid + i * 256;          // float4 index within 16KB tile
            bf16x4 o;
            o[0] = (__bf16)xv[i].x; o[1] = (__bf16)xv[i].y;
            o[2] = (__bf16)xv[i].z; o[3] = (__bf16)xv[i].w;
            const int r = p >> 4, ck = p & 15;
            *(bf16x4*)&xlds[r * XS + ck * 4] = o;
        }
        __syncthreads();

        // ---- issue next tile's global loads now; latency hides under e-loop ----
        if (st < 3) {
            const float4* xgn = xg + (st + 1) * 1024;
            #pragma unroll
            for (int i = 0; i < 4; ++i) xv[i] = xgn[tid + i * 256];
        }

        // ---- A fragments: 4 row-tiles, k-halves 0..31 / 32..63 ----
        bf16x8 a0[4], a1[4];
        #pragma unroll
        for (int t = 0; t < 4; ++t) {
            const int base = (t * 16 + n) * XS + q * 8;
            bf16x4 p0 = *(const bf16x4*)&xlds[base];
            bf16x4 p1 = *(const bf16x4*)&xlds[base + 4];
            bf16x4 p2 = *(const bf16x4*)&xlds[base + 32];
            bf16x4 p3 = *(const bf16x4*)&xlds[base + 36];
            a0[t] = __builtin_shufflevector(p0, p1, 0, 1, 2, 3, 4, 5, 6, 7);
            a1[t] = __builtin_shufflevector(p2, p3, 0, 1, 2, 3, 4, 5, 6, 7);
        }

        float rmax[4][4];
        #pragma unroll
        for (int t = 0; t < 4; ++t)
            #pragma unroll
            for (int r4 = 0; r4 < 4; ++r4) rmax[t][r4] = -3.0e38f;

        #pragma unroll
        for (int e = 0; e < 8; ++e) {
            #pragma unroll
            for (int t = 0; t < 4; ++t) {
                f32x4 acc = {0.f, 0.f, 0.f, 0.f};
                acc = __builtin_amdgcn_mfma_f32_16x16x32_bf16(a0[t], bf0[e], acc, 0, 0, 0);
                acc = __builtin_amdgcn_mfma_f32_16x16x32_bf16(a1[t], bf1[e], acc, 0, 0, 0);
                #pragma unroll
                for (int r4 = 0; r4 < 4; ++r4) {
                    // max(rmax, LeakyReLU(v)) = max3(rmax, v, 0.01*v) -> v_mul + v_max3
                    rmax[t][r4] = fmaxf(rmax[t][r4], fmaxf(acc[r4], 0.01f * acc[r4]));
                }
            }
        }

        // sum this s-tile's 64 rows: 16 rows per lane, butterfly across quads
        float s = 0.f;
        #pragma unroll
        for (int t = 0; t < 4; ++t)
            #pragma unroll
            for (int r4 = 0; r4 < 4; ++r4) s += rmax[t][r4];
        s += __shfl_xor(s, 16);
        s += __shfl_xor(s, 32);
        hsum += s;
        __syncthreads();   // xlds reused next s-tile
    }

    if (lane < 16) t0row[wave * 16 + lane] = hsum;
    __syncthreads();

    // ---- fc1 in-block: out1[b][j] = fc1_b[j] + sum_h t0[h] * fc1_w[j][h] ----
    if (wave == 0) {
        const int j = lane & 31, half = lane >> 5;
        float p = 0.f;
        #pragma unroll
        for (int i = 0; i < 32; ++i)
            p += t0row[half * 32 + i] * fc1_w[j * 64 + half * 32 + i];
        p += __shfl_xor(p, 32);
        if (half == 0) out1[b * 32 + j] = p + fc1_b[j];
    }
}

// Single block: BatchNorm (training-mode batch stats, biased var) + LeakyReLU + fc2
__global__ __launch_bounds__(512)
void bn_fc2(const float* __restrict__ out1, const float* __restrict__ gamma,
            const float* __restrict__ beta, const float* __restrict__ fc2_w,
            const float* __restrict__ fc2_b, float* __restrict__ out)
{
    __shared__ float psum[16][32];
    __shared__ float psumsq[16][32];
    __shared__ float sa[32], sc[32];

    const int tid = threadIdx.x;
    const int j   = tid & 31;
    const int sl  = tid >> 5;       // 16 slices of 32 batch rows

    float s = 0.f, ss = 0.f;
    #pragma unroll
    for (int i = 0; i < 32; ++i) {
        float v = out1[(sl * 32 + i) * 32 + j];
        s  += v;
        ss += v * v;
    }
    psum[sl][j]   = s;
    psumsq[sl][j] = ss;
    __syncthreads();

    if (tid < 32) {
        float S = 0.f, SS = 0.f;
        #pragma unroll
        for (int i = 0; i < 16; ++i) { S += psum[i][tid]; SS += psumsq[i][tid]; }
        const float mu  = S * (1.0f / 512.0f);
        const float var = SS * (1.0f / 512.0f) - mu * mu;   // biased variance
        const float rs  = rsqrtf(var + 1e-5f);
        const float a   = rs * gamma[tid];
        sa[tid] = a;
        sc[tid] = beta[tid] - mu * a;
    }
    __syncthreads();

    // one thread per batch row
    float acc = 0.f;
    #pragma unroll
    for (int jj = 0; jj < 32; ++jj) {
        float v = out1[tid * 32 + jj];
        float y = v * sa[jj] + sc[jj];
        y = fmaxf(y, 0.01f * y);    // LeakyReLU
        acc += y * fc2_w[jj];
    }
    out[tid] = acc + fc2_b[0];
}

extern "C" void kernel_launch(void* const* d_in, const int* in_sizes, int n_in,
                              void* d_out, int out_size, void* d_ws, size_t ws_size,
                              hipStream_t stream) {
    const float* X      = (const float*)d_in[0];
    const float* Wc     = (const float*)d_in[1];
    const float* fc1_w  = (const float*)d_in[2];
    const float* fc1_b  = (const float*)d_in[3];
    const float* gamma  = (const float*)d_in[4];
    const float* beta   = (const float*)d_in[5];
    const float* fc2_w  = (const float*)d_in[6];
    const float* fc2_b  = (const float*)d_in[7];

    float* out1 = (float*)d_ws;   // [512][32] fc1 outputs, 64 KB

    fused_main<<<512, 256, 0, stream>>>(X, Wc, fc1_w, fc1_b, out1);
    bn_fc2<<<1, 512, 0, stream>>>(out1, gamma, beta, fc2_w, fc2_b, (float*)d_out);
}